// Round 1
// baseline (326.128 us; speedup 1.0000x reference)
//
#include <hip/hip_runtime.h>
#include <stdint.h>

#define IN_DIM 512
#define CB_SIZE 8192
#define CB_DIM 16
#define NROWS 32768  // 8*4096

// ---------------- K0: codebook squared norms ----------------
__global__ __launch_bounds__(256) void csq_kernel(const float* __restrict__ cb,
                                                  float* __restrict__ csq) {
    int k = blockIdx.x * blockDim.x + threadIdx.x;
    if (k < CB_SIZE) {
        const float4* p = (const float4*)(cb + (size_t)k * CB_DIM);
        float s = 0.f;
#pragma unroll
        for (int j = 0; j < 4; ++j) {
            float4 v = p[j];
            s += v.x * v.x + v.y * v.y + v.z * v.z + v.w * v.w;
        }
        csq[k] = s;
    }
}

// ---------------- K1: projection, t' = -2 * (input @ W^T) ----------------
// Block = 256 threads = 4 waves; lane = row (64 rows/block); each wave does a
// 128-wide slice of the 512-d reduction; combine via LDS. Grid = 512 blocks.
__global__ __launch_bounds__(256) void proj_kernel(const float* __restrict__ in,
                                                   const float* __restrict__ W,
                                                   float* __restrict__ tprime) {
    __shared__ float part[3][64][20];  // stride 20 floats: 16B-aligned, few bank conflicts
    int lane = threadIdx.x & 63;
    int wave = __builtin_amdgcn_readfirstlane(threadIdx.x >> 6);
    int row = blockIdx.x * 64 + lane;

    const float4* inp = (const float4*)(in + (size_t)row * IN_DIM + wave * 128);
    float acc[16];
#pragma unroll
    for (int i = 0; i < 16; ++i) acc[i] = 0.f;

#pragma unroll 4
    for (int j = 0; j < 32; ++j) {
        float4 v = inp[j];
        const float* w0 = W + wave * 128 + j * 4;  // wave-uniform address
#pragma unroll
        for (int i = 0; i < 16; ++i) {
            const float* w = w0 + i * IN_DIM;
            acc[i] += v.x * w[0] + v.y * w[1] + v.z * w[2] + v.w * w[3];
        }
    }

    if (wave != 0) {
#pragma unroll
        for (int i = 0; i < 16; ++i) part[wave - 1][lane][i] = acc[i];
    }
    __syncthreads();
    if (wave == 0) {
#pragma unroll
        for (int i = 0; i < 16; ++i)
            acc[i] = -2.f * (acc[i] + part[0][lane][i] + part[1][lane][i] + part[2][lane][i]);
        float4* o = (float4*)(tprime + (size_t)row * 16);
#pragma unroll
        for (int j = 0; j < 4; ++j)
            o[j] = make_float4(acc[4 * j + 0], acc[4 * j + 1], acc[4 * j + 2], acc[4 * j + 3]);
    }
}

// ---------------- K2: argmin over codebook ----------------
// Block = 512 threads = 8 waves over 64 rows (lane = row). Wave w scans codes
// [w*1024, (w+1)*1024) with wave-uniform codebook/csq addresses (scalar-load
// friendly). score = ||c||^2 - 2 t.c  (t_sq dropped: constant per row).
// Cross-wave combine: packed (orderable score | idx) -> min preserves the
// reference's lowest-index tie-break.
__global__ __launch_bounds__(512) void argmin_kernel(const float* __restrict__ tprime,
                                                     const float* __restrict__ cb,
                                                     const float* __restrict__ csq,
                                                     int* __restrict__ out) {
    __shared__ unsigned long long red[8][64];
    int lane = threadIdx.x & 63;
    int wave = __builtin_amdgcn_readfirstlane(threadIdx.x >> 6);
    int row = blockIdx.x * 64 + lane;

    float t[16];
    const float4* tp = (const float4*)(tprime + (size_t)row * 16);
#pragma unroll
    for (int j = 0; j < 4; ++j) {
        float4 v = tp[j];
        t[4 * j + 0] = v.x; t[4 * j + 1] = v.y; t[4 * j + 2] = v.z; t[4 * j + 3] = v.w;
    }

    int kbase = wave * 1024;
    const float* cbp = cb + (size_t)kbase * CB_DIM;
    float best = 3.402823466e38f;
    int bidx = 0;

    for (int kk = 0; kk < 1024; kk += 2) {
        float s0 = csq[kbase + kk];
        float s1 = csq[kbase + kk + 1];
        const float* c0 = cbp + (size_t)kk * CB_DIM;
        const float* c1 = c0 + CB_DIM;
#pragma unroll
        for (int i = 0; i < 16; ++i) {
            s0 += t[i] * c0[i];
            s1 += t[i] * c1[i];
        }
        if (s0 < best) { best = s0; bidx = kbase + kk; }
        if (s1 < best) { best = s1; bidx = kbase + kk + 1; }
    }

    unsigned u = __float_as_uint(best);
    u = (u & 0x80000000u) ? ~u : (u | 0x80000000u);
    red[wave][lane] = ((unsigned long long)u << 32) | (unsigned)bidx;
    __syncthreads();

    if (wave == 0) {
        unsigned long long m = red[0][lane];
#pragma unroll
        for (int w = 1; w < 8; ++w) {
            unsigned long long x = red[w][lane];
            m = x < m ? x : m;
        }
        out[row] = (int)(m & 0xFFFFFFFFull);
    }
}

extern "C" void kernel_launch(void* const* d_in, const int* in_sizes, int n_in,
                              void* d_out, int out_size, void* d_ws, size_t ws_size,
                              hipStream_t stream) {
    const float* input = (const float*)d_in[0];  // (8,4096,512) fp32
    const float* W     = (const float*)d_in[1];  // (16,512) fp32
    const float* cb    = (const float*)d_in[2];  // (8192,16) fp32
    int* out = (int*)d_out;                      // (32768,) int32 labels

    float* tprime = (float*)d_ws;                       // 32768*16 fp32 = 2 MB
    float* csq    = tprime + (size_t)NROWS * CB_DIM;    // 8192 fp32

    csq_kernel<<<CB_SIZE / 256, 256, 0, stream>>>(cb, csq);
    proj_kernel<<<NROWS / 64, 256, 0, stream>>>(input, W, tprime);
    argmin_kernel<<<NROWS / 64, 512, 0, stream>>>(tprime, cb, csq, out);
}

// Round 5
// 285.791 us; speedup vs baseline: 1.1411x; 1.1411x over previous
//
#include <hip/hip_runtime.h>
#include <stdint.h>

#define IN_DIM 512
#define CB 8192
#define CD 16
#define NROWS 32768
#define DELTA 0.03f
#define FMAXV 3.402823466e38f

typedef short bf16x8 __attribute__((ext_vector_type(8)));
typedef float f32x4 __attribute__((ext_vector_type(4)));

__device__ inline unsigned short f2bf(float x) {
    unsigned u = __float_as_uint(x);
    unsigned r = u + 0x7FFFu + ((u >> 16) & 1u);   // RNE
    return (unsigned short)(r >> 16);
}
__device__ inline float bf2f(unsigned short h) { return __uint_as_float(((unsigned)h) << 16); }

// ---------------- K0: codebook squared norms (SOURCE-IDENTICAL to R1: bit-exact) ----------------
__global__ __launch_bounds__(256) void csq_kernel(const float* __restrict__ cb,
                                                  float* __restrict__ csq) {
    int k = blockIdx.x * blockDim.x + threadIdx.x;
    if (k < CB) {
        const float4* p = (const float4*)(cb + (size_t)k * CD);
        float s = 0.f;
#pragma unroll
        for (int j = 0; j < 4; ++j) {
            float4 v = p[j];
            s += v.x * v.x + v.y * v.y + v.z * v.z + v.w * v.w;
        }
        csq[k] = s;
    }
}

// ---------------- K1: pack codebook into MFMA B-fragment arrays (approx path only) ----------------
__global__ __launch_bounds__(256) void prep_kernel(const float* __restrict__ cb,
                                                   bf16x8* __restrict__ B1,
                                                   bf16x8* __restrict__ B2) {
    int id = blockIdx.x * 256 + threadIdx.x;  // 0..32767
    int slot = id & 63;
    int nt = id >> 6;
    int q = slot >> 4;
    int n = nt * 16 + (slot & 15);
    int d0 = (q & 1) * 8;
    const float* src = cb + (size_t)n * CD + d0;
    bf16x8 v1, v2;
#pragma unroll
    for (int j = 0; j < 8; ++j) {
        float x = src[j];
        unsigned short a = f2bf(x);
        unsigned short b = f2bf(x - bf2f(a));
        v1[j] = (short)a;
        v2[j] = (short)b;
    }
    B1[id] = v1;
    B2[id] = v2;
}

// ---------------- K2: projection — R1's EXACT arithmetic DAG, faster data movement ----------------
// Per (row,d): 4 chunk partials (wave=chunk, 128 dims, serial j=0..31 with the
// identical source expression), combined ((a0+a1)+a2)+a3, *(-2). Only loads
// changed: W staged in LDS; input double-buffered 4-deep. Loads don't alter bits.
__global__ __launch_bounds__(256) void proj_kernel(const float* __restrict__ in,
                                                   const float* __restrict__ W,
                                                   float* __restrict__ tprime) {
    __shared__ float WL[16 * 512];        // 32 KB
    __shared__ float part[3][64][17];
    {
        const float4* Wg = (const float4*)W;
        float4* WLv = (float4*)WL;
#pragma unroll
        for (int i = 0; i < 8; ++i) WLv[threadIdx.x + i * 256] = Wg[threadIdx.x + i * 256];
    }
    __syncthreads();
    int lane = threadIdx.x & 63;
    int wave = __builtin_amdgcn_readfirstlane(threadIdx.x >> 6);
    int row = blockIdx.x * 64 + lane;

    const float4* inp = (const float4*)(in + (size_t)row * IN_DIM + wave * 128);
    float acc[16];
#pragma unroll
    for (int i = 0; i < 16; ++i) acc[i] = 0.f;

    float4 bufA[4], bufB[4];
#pragma unroll
    for (int u = 0; u < 4; ++u) bufA[u] = inp[u];
#pragma unroll
    for (int jb = 0; jb < 8; ++jb) {
        float4* curb = (jb & 1) ? bufB : bufA;
        float4* nxtb = (jb & 1) ? bufA : bufB;
        if (jb < 7) {
#pragma unroll
            for (int u = 0; u < 4; ++u) nxtb[u] = inp[(jb + 1) * 4 + u];
        }
#pragma unroll
        for (int u = 0; u < 4; ++u) {
            int j = jb * 4 + u;
            float4 v = curb[u];
            const float* w0 = WL + wave * 128 + j * 4;
#pragma unroll
            for (int i = 0; i < 16; ++i) {
                const float* w = w0 + i * 512;
                acc[i] += v.x * w[0] + v.y * w[1] + v.z * w[2] + v.w * w[3];
            }
        }
    }

    if (wave != 0) {
#pragma unroll
        for (int i = 0; i < 16; ++i) part[wave - 1][lane][i] = acc[i];
    }
    __syncthreads();
    if (wave == 0) {
#pragma unroll
        for (int i = 0; i < 16; ++i)
            acc[i] = -2.f * (acc[i] + part[0][lane][i] + part[1][lane][i] + part[2][lane][i]);
        float4* o = (float4*)(tprime + (size_t)row * 16);
#pragma unroll
        for (int j = 0; j < 4; ++j)
            o[j] = make_float4(acc[4 * j + 0], acc[4 * j + 1], acc[4 * j + 2], acc[4 * j + 3]);
    }
}

// ---------------- K3: MFMA scan + best-2 argmin + flags (approx filter) ----------------
__global__ __launch_bounds__(512) void scan_kernel(
        const float* __restrict__ tprime, const float* __restrict__ csq,
        const bf16x8* __restrict__ B1, const bf16x8* __restrict__ B2,
        int* __restrict__ out, int* __restrict__ flags) {
    __shared__ float tbuf[64][17];
    __shared__ float m_s1[64][2];
    __shared__ float m_s2[64][2];
    __shared__ int   m_i1[64][2];

    int tid = threadIdx.x;
    int lane = tid & 63;
    int w = __builtin_amdgcn_readfirstlane(tid >> 6);
    int rowbase = blockIdx.x * 64;

    {
        int i0 = tid, i1 = tid + 512;
        tbuf[i0 >> 4][i0 & 15] = tprime[(size_t)rowbase * CD + i0];
        tbuf[i1 >> 4][i1 & 15] = tprime[(size_t)rowbase * CD + i1];
    }
    __syncthreads();

    int g = w & 3;
    int half = w >> 2;
    int q = lane >> 4;
    int col = lane & 15;

    bf16x8 A1;   // A[m=lane&15][k=q*8+j], [t1|t2] over the two K-halves
    {
        int arow = 16 * g + col;
        int d0 = (q & 1) * 8;
        bool lo = (q < 2);
#pragma unroll
        for (int j = 0; j < 8; ++j) {
            float x = tbuf[arow][d0 + j];
            unsigned short t1 = f2bf(x);
            unsigned short t2 = f2bf(x - bf2f(t1));
            A1[j] = (short)(lo ? t1 : t2);
        }
    }

    float s1v[4], s2v[4];
    int i1v[4];
#pragma unroll
    for (int r = 0; r < 4; ++r) { s1v[r] = FMAXV; s2v[r] = FMAXV; i1v[r] = 0; }
    int nt0 = half * 256;
    const bf16x8* p1 = B1 + (size_t)nt0 * 64 + lane;
    const bf16x8* p2 = B2 + (size_t)nt0 * 64 + lane;
    const float* csqp = csq + nt0 * 16 + col;

#pragma unroll 4
    for (int t = 0; t < 256; ++t) {
        bf16x8 b1 = p1[(size_t)t * 64];
        bf16x8 b2 = p2[(size_t)t * 64];
        float cs = csqp[t * 16];
        f32x4 acc = {cs, cs, cs, cs};
        acc = __builtin_amdgcn_mfma_f32_16x16x32_bf16(A1, b1, acc, 0, 0, 0);
        acc = __builtin_amdgcn_mfma_f32_16x16x32_bf16(A1, b2, acc, 0, 0, 0);
        int idx = (nt0 + t) * 16 + col;
#pragma unroll
        for (int r = 0; r < 4; ++r) {
            float s = acc[r];
            s2v[r] = fminf(s2v[r], fmaxf(s, s1v[r]));
            if (s < s1v[r]) i1v[r] = idx;
            s1v[r] = fminf(s1v[r], s);
        }
    }

#pragma unroll
    for (int m = 1; m < 16; m <<= 1) {
#pragma unroll
        for (int r = 0; r < 4; ++r) {
            float os1 = __shfl_xor(s1v[r], m, 64);
            int   oi1 = __shfl_xor(i1v[r], m, 64);
            float os2 = __shfl_xor(s2v[r], m, 64);
            s2v[r] = fminf(fminf(s2v[r], os2), fmaxf(s1v[r], os1));
            bool take = (os1 < s1v[r]) || (os1 == s1v[r] && oi1 < i1v[r]);
            if (take) { s1v[r] = os1; i1v[r] = oi1; }
        }
    }
    if (col == 0) {
#pragma unroll
        for (int r = 0; r < 4; ++r) {
            int rl = 16 * g + 4 * q + r;   // C/D row = quad*4 + reg
            m_s1[rl][half] = s1v[r];
            m_i1[rl][half] = i1v[r];
            m_s2[rl][half] = s2v[r];
        }
    }
    __syncthreads();
    if (tid < 64) {
        float a1s = m_s1[tid][0], b1s = m_s1[tid][1];
        int   ai = m_i1[tid][0], bi = m_i1[tid][1];
        float a2s = m_s2[tid][0], b2s = m_s2[tid][1];
        bool take = b1s < a1s;
        float s1 = take ? b1s : a1s;
        int i1 = take ? bi : ai;
        float s2 = fminf(fminf(a2s, b2s), fmaxf(a1s, b1s));
        out[rowbase + tid] = i1;
        flags[rowbase + tid] = (s2 - s1 < DELTA) ? 1 : 0;
    }
}

// ---------------- K4: fallback — R1's fp32 arithmetic, bit-exact ----------------
// score = serial FMA chain: s = fma(t15,c15, ... fma(t0,c0, csq[k])), ascending k
// per lane, strict <, packed-u64 min across lanes (lowest score, lowest index).
// This reproduces R1's passing labels exactly on every flagged row.
__global__ __launch_bounds__(64) void fallback_kernel(const float* __restrict__ tprime,
                                                      const float* __restrict__ cb,
                                                      const float* __restrict__ csq,
                                                      const int* __restrict__ flags,
                                                      int* __restrict__ out) {
    int lane = threadIdx.x;
    int rowbase = blockIdx.x * 64;
    int f = flags[rowbase + lane];
    unsigned long long mask = __ballot(f != 0);
    while (mask) {
        int bit = __ffsll(mask) - 1;
        mask &= mask - 1;
        int row = rowbase + bit;
        float tp[16];
        const float* tpp = tprime + (size_t)row * CD;
#pragma unroll
        for (int d = 0; d < 16; ++d) tp[d] = tpp[d];  // wave-uniform -> s_load
        float best = FMAXV;
        int bidx = 0;
        for (int k0 = 0; k0 < CB; k0 += 128) {
            int ka = k0 + lane;
            int kb = ka + 64;
            float s0 = csq[ka];
            float s1 = csq[kb];
            const float* c0 = cb + (size_t)ka * CD;
            const float* c1 = cb + (size_t)kb * CD;
#pragma unroll
            for (int d = 0; d < 16; ++d) {
                s0 += tp[d] * c0[d];
                s1 += tp[d] * c1[d];
            }
            if (s0 < best) { best = s0; bidx = ka; }
            if (s1 < best) { best = s1; bidx = kb; }
        }
        unsigned u = __float_as_uint(best);
        u = (u & 0x80000000u) ? ~u : (u | 0x80000000u);
        unsigned long long key = ((unsigned long long)u << 32) | (unsigned)bidx;
#pragma unroll
        for (int m = 1; m < 64; m <<= 1) {
            double od = __shfl_xor(__longlong_as_double((long long)key), m, 64);
            unsigned long long o = (unsigned long long)__double_as_longlong(od);
            key = o < key ? o : key;
        }
        if (lane == 0) out[row] = (int)(key & 0xFFFFFFFFull);
    }
}

extern "C" void kernel_launch(void* const* d_in, const int* in_sizes, int n_in,
                              void* d_out, int out_size, void* d_ws, size_t ws_size,
                              hipStream_t stream) {
    const float* input = (const float*)d_in[0];  // (8,4096,512) fp32
    const float* W     = (const float*)d_in[1];  // (16,512) fp32
    const float* cb    = (const float*)d_in[2];  // (8192,16) fp32
    int* out = (int*)d_out;                      // (32768,) int32 labels

    float*  tprime = (float*)d_ws;                        // 2 MB
    float*  csq    = tprime + (size_t)NROWS * CD;         // 32 KB
    int*    flags  = (int*)(csq + CB);                    // 128 KB
    bf16x8* B1     = (bf16x8*)(flags + NROWS);            // 512 KB each
    bf16x8* B2     = B1 + 32768;

    csq_kernel<<<CB / 256, 256, 0, stream>>>(cb, csq);
    prep_kernel<<<32768 / 256, 256, 0, stream>>>(cb, B1, B2);
    proj_kernel<<<NROWS / 64, 256, 0, stream>>>(input, W, tprime);
    scan_kernel<<<NROWS / 64, 512, 0, stream>>>(tprime, csq, B1, B2, out, flags);
    fallback_kernel<<<NROWS / 64, 64, 0, stream>>>(tprime, cb, csq, flags, out);
}

// Round 6
// 233.545 us; speedup vs baseline: 1.3964x; 1.2237x over previous
//
#include <hip/hip_runtime.h>
#include <stdint.h>

#define IN_DIM 512
#define CB 8192
#define CD 16
#define NROWS 32768
#define DELTA 2e-3f
#define FMAXV 3.402823466e38f

typedef short bf16x8 __attribute__((ext_vector_type(8)));
typedef float f32x4 __attribute__((ext_vector_type(4)));

__device__ inline unsigned short f2bf(float x) {
    unsigned u = __float_as_uint(x);
    unsigned r = u + 0x7FFFu + ((u >> 16) & 1u);   // RNE
    return (unsigned short)(r >> 16);
}
__device__ inline float bf2f(unsigned short h) { return __uint_as_float(((unsigned)h) << 16); }

// ---------------- K0: codebook squared norms (SOURCE-IDENTICAL to R1: bit-exact) ----------------
__global__ __launch_bounds__(256) void csq_kernel(const float* __restrict__ cb,
                                                  float* __restrict__ csq) {
    int k = blockIdx.x * blockDim.x + threadIdx.x;
    if (k < CB) {
        const float4* p = (const float4*)(cb + (size_t)k * CD);
        float s = 0.f;
#pragma unroll
        for (int j = 0; j < 4; ++j) {
            float4 v = p[j];
            s += v.x * v.x + v.y * v.y + v.z * v.z + v.w * v.w;
        }
        csq[k] = s;
    }
}

// ---------------- K1: pack codebook into MFMA B-fragment arrays ----------------
// 3-term bf16 split c = c1 + c2 + c3 (exact to 2^-27 rel).
// Slot id = nt*64 + lane; q=lane>>4, n=nt*16+(lane&15), d=(q&1)*8+j.
// B1 = [c1|c1], B2 = [c2|c2], B3 = [c3|c1]  (pairs with A2 = [t1|t3]).
__global__ __launch_bounds__(256) void prep_kernel(const float* __restrict__ cb,
                                                   bf16x8* __restrict__ B1,
                                                   bf16x8* __restrict__ B2,
                                                   bf16x8* __restrict__ B3) {
    int id = blockIdx.x * 256 + threadIdx.x;  // 0..32767
    int slot = id & 63;
    int nt = id >> 6;
    int q = slot >> 4;
    int n = nt * 16 + (slot & 15);
    int d0 = (q & 1) * 8;
    bool lo = (q < 2);
    const float* src = cb + (size_t)n * CD + d0;
    bf16x8 v1, v2, v3;
#pragma unroll
    for (int j = 0; j < 8; ++j) {
        float x = src[j];
        unsigned short a = f2bf(x);
        float r = x - bf2f(a);
        unsigned short b = f2bf(r);
        float r2 = r - bf2f(b);
        unsigned short c = f2bf(r2);
        v1[j] = (short)a;
        v2[j] = (short)b;
        v3[j] = (short)(lo ? c : a);    // B3 = [c3 | c1]
    }
    B1[id] = v1;
    B2[id] = v2;
    B3[id] = v3;
}

// ---------------- K2: projection — R1's EXACT arithmetic DAG, upfront-loaded ----------------
// Per (row,d): 4 chunk partials (wave=chunk, 128 dims, serial j with the
// identical source expression), combined ((a0+a1)+a2)+a3, *(-2).
// All 32 float4 loads issued upfront (max MLP); loads don't alter bits.
__global__ __launch_bounds__(256, 2) void proj_kernel(const float* __restrict__ in,
                                                      const float* __restrict__ W,
                                                      float* __restrict__ tprime) {
    __shared__ float WL[16 * 512];        // 32 KB
    __shared__ float part[3][64][17];
    {
        const float4* Wg = (const float4*)W;
        float4* WLv = (float4*)WL;
#pragma unroll
        for (int i = 0; i < 8; ++i) WLv[threadIdx.x + i * 256] = Wg[threadIdx.x + i * 256];
    }
    __syncthreads();
    int lane = threadIdx.x & 63;
    int wave = __builtin_amdgcn_readfirstlane(threadIdx.x >> 6);
    int row = blockIdx.x * 64 + lane;

    const float4* inp = (const float4*)(in + (size_t)row * IN_DIM + wave * 128);
    float4 iv[32];
#pragma unroll
    for (int u = 0; u < 32; ++u) iv[u] = inp[u];

    float acc[16];
#pragma unroll
    for (int i = 0; i < 16; ++i) acc[i] = 0.f;

#pragma unroll
    for (int j = 0; j < 32; ++j) {
        float4 v = iv[j];
        const float* w0 = WL + wave * 128 + j * 4;
#pragma unroll
        for (int i = 0; i < 16; ++i) {
            const float* w = w0 + i * 512;
            acc[i] += v.x * w[0] + v.y * w[1] + v.z * w[2] + v.w * w[3];
        }
    }

    if (wave != 0) {
#pragma unroll
        for (int i = 0; i < 16; ++i) part[wave - 1][lane][i] = acc[i];
    }
    __syncthreads();
    if (wave == 0) {
#pragma unroll
        for (int i = 0; i < 16; ++i)
            acc[i] = -2.f * (acc[i] + part[0][lane][i] + part[1][lane][i] + part[2][lane][i]);
        float4* o = (float4*)(tprime + (size_t)row * 16);
#pragma unroll
        for (int j = 0; j < 4; ++j)
            o[j] = make_float4(acc[4 * j + 0], acc[4 * j + 1], acc[4 * j + 2], acc[4 * j + 3]);
    }
}

// ---------------- K3: 3-MFMA scan + best-2 argmin + flags ----------------
// 1024 blocks x 512 threads; 32 rows/block. Wave w: rowgroup g=w&1 (16 rows),
// quarter q4=w>>1 (128 tiles = 2048 codes). score = ||c||^2 - 2 t.c with
// error <= ~2e-4 vs R1's fp32 chain (3-MFMA split covers all terms >= 2^-18).
__global__ __launch_bounds__(512, 6) void scan_kernel(
        const float* __restrict__ tprime, const float* __restrict__ csq,
        const bf16x8* __restrict__ B1, const bf16x8* __restrict__ B2,
        const bf16x8* __restrict__ B3,
        int* __restrict__ out, int* __restrict__ flags) {
    __shared__ float tbuf[32][17];
    __shared__ float m_s1[32][4];
    __shared__ float m_s2[32][4];
    __shared__ int   m_i1[32][4];

    int tid = threadIdx.x;
    int lane = tid & 63;
    int w = __builtin_amdgcn_readfirstlane(tid >> 6);
    int rowbase = blockIdx.x * 32;

    tbuf[tid >> 4][tid & 15] = tprime[(size_t)rowbase * CD + tid];
    __syncthreads();

    int g = w & 1;
    int q4 = w >> 1;            // quarter 0..3
    int q = lane >> 4;
    int col = lane & 15;

    bf16x8 A1, A2;   // A[m=lane&15][k=q*8+j]; A1=[t1|t2], A2=[t1|t3]
    {
        int arow = 16 * g + col;
        int d0 = (q & 1) * 8;
        bool lo = (q < 2);
#pragma unroll
        for (int j = 0; j < 8; ++j) {
            float x = tbuf[arow][d0 + j];
            unsigned short t1 = f2bf(x);
            float r = x - bf2f(t1);
            unsigned short t2 = f2bf(r);
            float r2 = r - bf2f(t2);
            unsigned short t3 = f2bf(r2);
            A1[j] = (short)(lo ? t1 : t2);
            A2[j] = (short)(lo ? t1 : t3);
        }
    }

    float s1v[4], s2v[4];
    int i1v[4];
#pragma unroll
    for (int r = 0; r < 4; ++r) { s1v[r] = FMAXV; s2v[r] = FMAXV; i1v[r] = 0; }
    int nt0 = q4 * 128;
    const bf16x8* p1 = B1 + (size_t)nt0 * 64 + lane;
    const bf16x8* p2 = B2 + (size_t)nt0 * 64 + lane;
    const bf16x8* p3 = B3 + (size_t)nt0 * 64 + lane;
    const float* csqp = csq + nt0 * 16 + col;

#pragma unroll 2
    for (int t = 0; t < 128; ++t) {
        bf16x8 b1 = p1[(size_t)t * 64];
        bf16x8 b2 = p2[(size_t)t * 64];
        bf16x8 b3 = p3[(size_t)t * 64];
        float cs = csqp[t * 16];
        f32x4 acc = {cs, cs, cs, cs};
        acc = __builtin_amdgcn_mfma_f32_16x16x32_bf16(A1, b1, acc, 0, 0, 0);
        acc = __builtin_amdgcn_mfma_f32_16x16x32_bf16(A1, b2, acc, 0, 0, 0);
        acc = __builtin_amdgcn_mfma_f32_16x16x32_bf16(A2, b3, acc, 0, 0, 0);
        int idx = (nt0 + t) * 16 + col;
#pragma unroll
        for (int r = 0; r < 4; ++r) {
            float s = acc[r];
            s2v[r] = fminf(s2v[r], fmaxf(s, s1v[r]));
            if (s < s1v[r]) i1v[r] = idx;
            s1v[r] = fminf(s1v[r], s);
        }
    }

    // reduce across the 16 columns (lane bits 0-3)
#pragma unroll
    for (int m = 1; m < 16; m <<= 1) {
#pragma unroll
        for (int r = 0; r < 4; ++r) {
            float os1 = __shfl_xor(s1v[r], m, 64);
            int   oi1 = __shfl_xor(i1v[r], m, 64);
            float os2 = __shfl_xor(s2v[r], m, 64);
            s2v[r] = fminf(fminf(s2v[r], os2), fmaxf(s1v[r], os1));
            bool take = (os1 < s1v[r]) || (os1 == s1v[r] && oi1 < i1v[r]);
            if (take) { s1v[r] = os1; i1v[r] = oi1; }
        }
    }
    if (col == 0) {
#pragma unroll
        for (int r = 0; r < 4; ++r) {
            int rl = 16 * g + 4 * q + r;   // C/D row = quad*4 + reg
            m_s1[rl][q4] = s1v[r];
            m_i1[rl][q4] = i1v[r];
            m_s2[rl][q4] = s2v[r];
        }
    }
    __syncthreads();
    if (tid < 32) {
        float best = FMAXV, s2 = FMAXV;
        int idx = 0;
#pragma unroll
        for (int qq = 0; qq < 4; ++qq) {   // ascending quarter = ascending code range
            float a1 = m_s1[tid][qq];
            int   ai = m_i1[tid][qq];
            float a2 = m_s2[tid][qq];
            s2 = fminf(fminf(s2, a2), fmaxf(best, a1));
            bool take = (a1 < best) || (a1 == best && ai < idx);
            if (take) { best = a1; idx = ai; }
        }
        out[rowbase + tid] = idx;
        flags[rowbase + tid] = (s2 - best < DELTA) ? 1 : 0;
    }
}

// ---------------- K4: fallback — R1's fp32 arithmetic, bit-exact, 1 block/row ----------------
// Per-code serial FMA chain s = csq[k] + sum_d tp[d]*c[d] (R1's expression),
// strict < per-thread ascending k, packed-u64 min across threads: label-order
// independent of parallel layout -> reproduces R1's labels exactly.
__global__ __launch_bounds__(256) void fallback_kernel(const float* __restrict__ tprime,
                                                       const float* __restrict__ cb,
                                                       const float* __restrict__ csq,
                                                       const int* __restrict__ flags,
                                                       int* __restrict__ out) {
    int row = blockIdx.x;
    if (flags[row] == 0) return;          // block-uniform
    __shared__ unsigned long long red[4];
    int tid = threadIdx.x;
    int lane = tid & 63;
    int w = tid >> 6;

    float tp[16];
    const float* tpp = tprime + (size_t)row * CD;
#pragma unroll
    for (int d = 0; d < 16; ++d) tp[d] = tpp[d];   // uniform -> broadcast

    float best = FMAXV;
    int bidx = 0;
#pragma unroll 2
    for (int i = 0; i < 32; ++i) {
        int k = tid + 256 * i;            // ascending per thread
        const float* cp = cb + (size_t)k * CD;
        float s = csq[k];
#pragma unroll
        for (int d = 0; d < 16; ++d) s += tp[d] * cp[d];
        if (s < best) { best = s; bidx = k; }
    }
    unsigned u = __float_as_uint(best);
    u = (u & 0x80000000u) ? ~u : (u | 0x80000000u);
    unsigned long long key = ((unsigned long long)u << 32) | (unsigned)bidx;
#pragma unroll
    for (int m = 1; m < 64; m <<= 1) {
        double od = __shfl_xor(__longlong_as_double((long long)key), m, 64);
        unsigned long long o = (unsigned long long)__double_as_longlong(od);
        key = o < key ? o : key;
    }
    if (lane == 0) red[w] = key;
    __syncthreads();
    if (tid == 0) {
        unsigned long long m = red[0];
#pragma unroll
        for (int i = 1; i < 4; ++i) { unsigned long long x = red[i]; m = x < m ? x : m; }
        out[row] = (int)(m & 0xFFFFFFFFull);
    }
}

extern "C" void kernel_launch(void* const* d_in, const int* in_sizes, int n_in,
                              void* d_out, int out_size, void* d_ws, size_t ws_size,
                              hipStream_t stream) {
    const float* input = (const float*)d_in[0];  // (8,4096,512) fp32
    const float* W     = (const float*)d_in[1];  // (16,512) fp32
    const float* cb    = (const float*)d_in[2];  // (8192,16) fp32
    int* out = (int*)d_out;                      // (32768,) int32 labels

    float*  tprime = (float*)d_ws;                        // 2 MB
    float*  csq    = tprime + (size_t)NROWS * CD;         // 32 KB
    int*    flags  = (int*)(csq + CB);                    // 128 KB
    bf16x8* B1     = (bf16x8*)(flags + NROWS);            // 512 KB each
    bf16x8* B2     = B1 + 32768;
    bf16x8* B3     = B2 + 32768;

    csq_kernel<<<CB / 256, 256, 0, stream>>>(cb, csq);
    prep_kernel<<<32768 / 256, 256, 0, stream>>>(cb, B1, B2, B3);
    proj_kernel<<<NROWS / 64, 256, 0, stream>>>(input, W, tprime);
    scan_kernel<<<NROWS / 32, 512, 0, stream>>>(tprime, csq, B1, B2, B3, out, flags);
    fallback_kernel<<<NROWS, 256, 0, stream>>>(tprime, cb, csq, flags, out);
}